// Round 9
// baseline (223.059 us; speedup 1.0000x reference)
//
#include <hip/hip_runtime.h>
#include <cstdint>

// NT-Xent loss via symmetric bf16-MFMA Gram + fused exp/row-sum epilogue.
//  S[r] = sum_{c!=r} exp((dot(n_r,n_c)-1)/tau); lse[r] = log(S[r]) + 1/tau.
//  R9: NO-LDS K-loop. E (8 MB) is L3-resident and the MFMA fragment pattern
//      is directly loadable from global (bf16x8 = 16B/lane), so LDS staging
//      bought nothing but 17 barrier-drains/tile + 4.26M bank conflicts
//      (m169 lesson: don't stage what cache-fits). Double-buffered fragment
//      registers (static names), zero __syncthreads in the K-loop.
//      T1 swizzle REVERTED (R8: regressed).
// ws: [0, 8 MiB) E bf16 8192x512 | S[8192] f32 | pd[4096] f32 (pair cosines)

#define B_ROWS 4096
#define NROWS  8192
#define DIM    512
#define NTILES 2080   // 64 diag + 2016 strict-upper 128x128 tiles

typedef unsigned short u16;

constexpr float INV_TAU    = 1.0f / 0.07f;
constexpr float POS_THRESH = 0.2f;
constexpr int BM = 128, BN = 128;

using f32x4  = __attribute__((ext_vector_type(4))) float;
using bf16x8 = __attribute__((ext_vector_type(8))) short;

static __device__ __forceinline__ u16 f2bf(float f) {
  union { float f; uint32_t u; } v; v.f = f;
  uint32_t r = v.u + 0x7fffu + ((v.u >> 16) & 1u);  // RNE
  return (u16)(r >> 16);
}

// ---- knorm2: one wave per pair k. Normalize rows k and k+B to bf16,
//      compute fp32 pair cosine, zero S. (unchanged) ----
__global__ __launch_bounds__(256) void knorm2(const float* __restrict__ ei,
                                              const float* __restrict__ ej,
                                              u16* __restrict__ E,
                                              float* __restrict__ S,
                                              float* __restrict__ pd) {
  const int k    = (blockIdx.x * 256 + threadIdx.x) >> 6;  // pair 0..4095
  const int lane = threadIdx.x & 63;
  const float4* pi = (const float4*)(ei + (size_t)k * DIM);
  const float4* pj = (const float4*)(ej + (size_t)k * DIM);
  float4 a[2] = { pi[lane * 2], pi[lane * 2 + 1] };
  float4 b[2] = { pj[lane * 2], pj[lane * 2 + 1] };
  float si = 0.f, sj = 0.f, dot = 0.f;
#pragma unroll
  for (int h = 0; h < 2; ++h) {
    si  += a[h].x*a[h].x + a[h].y*a[h].y + a[h].z*a[h].z + a[h].w*a[h].w;
    sj  += b[h].x*b[h].x + b[h].y*b[h].y + b[h].z*b[h].z + b[h].w*b[h].w;
    dot += a[h].x*b[h].x + a[h].y*b[h].y + a[h].z*b[h].z + a[h].w*b[h].w;
  }
#pragma unroll
  for (int m = 1; m < 64; m <<= 1) {
    si += __shfl_xor(si, m); sj += __shfl_xor(sj, m); dot += __shfl_xor(dot, m);
  }
  const float invi = 1.0f / sqrtf(si);
  const float invj = 1.0f / sqrtf(sj);
  union { u16 us[8]; uint4 v; } pk;
#pragma unroll
  for (int h = 0; h < 2; ++h) {
    pk.us[h*4+0] = f2bf(a[h].x * invi); pk.us[h*4+1] = f2bf(a[h].y * invi);
    pk.us[h*4+2] = f2bf(a[h].z * invi); pk.us[h*4+3] = f2bf(a[h].w * invi);
  }
  ((uint4*)(E + (size_t)k * DIM))[lane] = pk.v;
#pragma unroll
  for (int h = 0; h < 2; ++h) {
    pk.us[h*4+0] = f2bf(b[h].x * invj); pk.us[h*4+1] = f2bf(b[h].y * invj);
    pk.us[h*4+2] = f2bf(b[h].z * invj); pk.us[h*4+3] = f2bf(b[h].w * invj);
  }
  ((uint4*)(E + (size_t)(k + B_ROWS) * DIM))[lane] = pk.v;
  if (lane == 0) {
    pd[k] = dot * invi * invj;
    S[k] = 0.0f; S[k + B_ROWS] = 0.0f;
  }
}

// ---- symmetric Gram-GEMM, fragments direct from global (no LDS, no barriers) ----
__global__ __launch_bounds__(256) void ksimlse(const u16* __restrict__ E,
                                               float* __restrict__ S) {
  // triangular tile map: block t -> (I, J), J >= I, 64x64 tile grid
  const int t0 = blockIdx.x;
  int I = (int)(64.5f - sqrtf(4160.25f - 2.0f * (float)t0));
  if (I > 63) I = 63;
  int base = (129 * I - I * I) >> 1;
  if (base > t0) { --I; base = (129 * I - I * I) >> 1; }
  else {
    int nb = (129 * (I + 1) - (I + 1) * (I + 1)) >> 1;
    if (nb <= t0) { ++I; base = nb; }
  }
  const int J = I + (t0 - base);
  const int brow = I * BM, bcol = J * BN;
  const bool diag = (I == J);

  const int tid  = threadIdx.x;
  const int wid  = tid >> 6;
  const int lane = tid & 63;
  const int wr   = (wid >> 1) * 64;   // wave row offset in tile
  const int wc   = (wid & 1) * 64;    // wave col offset in tile
  const int g    = lane >> 4;         // k-group
  const int lc   = lane & 15;         // fragment row-in-16

  // per-lane fragment base pointers: row (brow+wr+mi*16+lc), col g*8
  const u16* aP[4];
  const u16* bP[4];
#pragma unroll
  for (int mi = 0; mi < 4; ++mi)
    aP[mi] = E + (size_t)(brow + wr + mi * 16 + lc) * DIM + g * 8;
#pragma unroll
  for (int ni = 0; ni < 4; ++ni)
    bP[ni] = E + (size_t)(bcol + wc + ni * 16 + lc) * DIM + g * 8;

  f32x4 acc[4][4] = {};

  bf16x8 aX[4], bX[4], aY[4], bY[4];   // two static fragment sets (rule #20)
#pragma unroll
  for (int q = 0; q < 4; ++q) {
    aX[q] = *(const bf16x8*)(aP[q]);
    bX[q] = *(const bf16x8*)(bP[q]);
  }

#pragma unroll 1
  for (int t = 0; t < 16; t += 2) {     // two K-steps (k = t*32, (t+1)*32) per iter
    const int k1 = (t + 1) * 32;
    if (t + 1 < 16) {
#pragma unroll
      for (int q = 0; q < 4; ++q) {
        aY[q] = *(const bf16x8*)(aP[q] + k1);
        bY[q] = *(const bf16x8*)(bP[q] + k1);
      }
    }
#pragma unroll
    for (int mi = 0; mi < 4; ++mi)
#pragma unroll
      for (int ni = 0; ni < 4; ++ni)
        acc[mi][ni] = __builtin_amdgcn_mfma_f32_16x16x32_bf16(
            aX[mi], bX[ni], acc[mi][ni], 0, 0, 0);

    const int k2 = (t + 2) * 32;
    if (t + 2 < 16) {
#pragma unroll
      for (int q = 0; q < 4; ++q) {
        aX[q] = *(const bf16x8*)(aP[q] + k2);
        bX[q] = *(const bf16x8*)(bP[q] + k2);
      }
    }
#pragma unroll
    for (int mi = 0; mi < 4; ++mi)
#pragma unroll
      for (int ni = 0; ni < 4; ++ni)
        acc[mi][ni] = __builtin_amdgcn_mfma_f32_16x16x32_bf16(
            aY[mi], bY[ni], acc[mi][ni], 0, 0, 0);
  }

  // epilogue: C/D layout col=lane&15, row=(lane>>4)*4+j  [m89/m91]
  float cs[4] = {0.f, 0.f, 0.f, 0.f};
#pragma unroll
  for (int mi = 0; mi < 4; ++mi) {
#pragma unroll
    for (int j = 0; j < 4; ++j) {
      const int Rg = brow + wr + mi * 16 + g * 4 + j;
      float rs = 0.0f;
#pragma unroll
      for (int ni = 0; ni < 4; ++ni) {
        const int Cg = bcol + wc + ni * 16 + lc;
        float e = __expf((acc[mi][ni][j] - 1.0f) * INV_TAU);
        if (diag && Rg == Cg) e = 0.0f;
        rs += e;
        cs[ni] += e;
      }
      rs += __shfl_xor(rs, 1);
      rs += __shfl_xor(rs, 2);
      rs += __shfl_xor(rs, 4);
      rs += __shfl_xor(rs, 8);
      if (lc == j) atomicAdd(&S[Rg], rs);
    }
  }
  if (!diag) {  // column sums -> S[c] (the mirrored half)
#pragma unroll
    for (int ni = 0; ni < 4; ++ni) {
      float c = cs[ni];
      c += __shfl_xor(c, 16);
      c += __shfl_xor(c, 32);
      if (g == 0) atomicAdd(&S[bcol + wc + ni * 16 + lc], c);
    }
  }
}

// ---- final: single block folds per-pair loss, no global atomics ----
__global__ __launch_bounds__(256) void kfinal256(const float* __restrict__ dist,
                                                 const float* __restrict__ pd,
                                                 const float* __restrict__ S,
                                                 float* __restrict__ out) {
  const int tid = threadIdx.x;
  float ls = 0.0f, nv = 0.0f;
  for (int it = 0; it < B_ROWS / 256; ++it) {
    const int k = it * 256 + tid;
    if (dist[k] < POS_THRESH) {
      ls += logf(S[k]) + logf(S[k + B_ROWS]) + 2.0f * INV_TAU
          - 2.0f * pd[k] * INV_TAU;
      nv += 2.0f;
    }
  }
#pragma unroll
  for (int m = 1; m < 64; m <<= 1) {
    ls += __shfl_xor(ls, m); nv += __shfl_xor(nv, m);
  }
  __shared__ float sl[4], sn[4];
  if ((tid & 63) == 0) { sl[tid >> 6] = ls; sn[tid >> 6] = nv; }
  __syncthreads();
  if (tid == 0) {
    const float L = sl[0] + sl[1] + sl[2] + sl[3];
    const float N = sn[0] + sn[1] + sn[2] + sn[3];
    out[0] = (N > 0.0f) ? (L / fmaxf(N, 1.0f)) : 0.0f;
  }
}

extern "C" void kernel_launch(void* const* d_in, const int* in_sizes, int n_in,
                              void* d_out, int out_size, void* d_ws, size_t ws_size,
                              hipStream_t stream) {
  const float* ei   = (const float*)d_in[0];
  const float* ej   = (const float*)d_in[1];
  const float* dist = (const float*)d_in[2];
  float* out = (float*)d_out;

  u16*   E  = (u16*)d_ws;
  float* S  = (float*)((char*)d_ws + (size_t)NROWS * DIM * sizeof(u16));
  float* pd = S + NROWS;

  knorm2<<<B_ROWS / 4, 256, 0, stream>>>(ei, ej, E, S, pd);
  ksimlse<<<NTILES, 256, 0, stream>>>(E, S);
  kfinal256<<<1, 256, 0, stream>>>(dist, pd, S, out);
}

// Round 10
// 148.746 us; speedup vs baseline: 1.4996x; 1.4996x over previous
//
#include <hip/hip_runtime.h>
#include <cstdint>

// NT-Xent loss via symmetric bf16-MFMA Gram + fused exp/row-sum epilogue.
//  S[r] = sum_{c!=r} exp((dot(n_r,n_c)-1)/tau); lse[r] = log(S[r]) + 1/tau.
//  R10: depth-3 staging pipeline with COUNTED vmcnt (T4 on the R6 skeleton).
//    3 LDS buffers; iter t issues stage(t+2), then ds_read+MFMA on buf[t%3],
//    then `s_waitcnt vmcnt(4); s_barrier` — waits only for stage(t+1),
//    issued a full iteration earlier; stage(t+2)'s 4 loads stay in flight.
//    Never vmcnt(0) in the main loop (drain only at t=KSTEPS-2).
//    (R8 XCD swizzle reverted: regressed. R9 no-LDS reverted: regressed.)
// ws: [0, 8 MiB) E bf16 8192x512 | S[8192] f32 | pd[4096] f32 (pair cosines)

#define B_ROWS 4096
#define NROWS  8192
#define DIM    512
#define NTILES 2080   // 64 diag + 2016 strict-upper 128x128 tiles

typedef unsigned short u16;

constexpr float INV_TAU    = 1.0f / 0.07f;
constexpr float POS_THRESH = 0.2f;
constexpr int BM = 128, BN = 128, BK = 32;
constexpr int KSTEPS = DIM / BK;   // 16

using f32x4  = __attribute__((ext_vector_type(4))) float;
using bf16x8 = __attribute__((ext_vector_type(8))) short;

static __device__ __forceinline__ u16 f2bf(float f) {
  union { float f; uint32_t u; } v; v.f = f;
  uint32_t r = v.u + 0x7fffu + ((v.u >> 16) & 1u);  // RNE
  return (u16)(r >> 16);
}

static __device__ __forceinline__ void gload16(const u16* g, void* l) {
  __builtin_amdgcn_global_load_lds(
      (const __attribute__((address_space(1))) void*)g,
      (__attribute__((address_space(3))) void*)l, 16, 0, 0);
}

// ---- knorm2: one wave per pair k. Normalize rows k and k+B to bf16,
//      compute fp32 pair cosine, zero S. (unchanged from R6) ----
__global__ __launch_bounds__(256) void knorm2(const float* __restrict__ ei,
                                              const float* __restrict__ ej,
                                              u16* __restrict__ E,
                                              float* __restrict__ S,
                                              float* __restrict__ pd) {
  const int k    = (blockIdx.x * 256 + threadIdx.x) >> 6;  // pair 0..4095
  const int lane = threadIdx.x & 63;
  const float4* pi = (const float4*)(ei + (size_t)k * DIM);
  const float4* pj = (const float4*)(ej + (size_t)k * DIM);
  float4 a[2] = { pi[lane * 2], pi[lane * 2 + 1] };
  float4 b[2] = { pj[lane * 2], pj[lane * 2 + 1] };
  float si = 0.f, sj = 0.f, dot = 0.f;
#pragma unroll
  for (int h = 0; h < 2; ++h) {
    si  += a[h].x*a[h].x + a[h].y*a[h].y + a[h].z*a[h].z + a[h].w*a[h].w;
    sj  += b[h].x*b[h].x + b[h].y*b[h].y + b[h].z*b[h].z + b[h].w*b[h].w;
    dot += a[h].x*b[h].x + a[h].y*b[h].y + a[h].z*b[h].z + a[h].w*b[h].w;
  }
#pragma unroll
  for (int m = 1; m < 64; m <<= 1) {
    si += __shfl_xor(si, m); sj += __shfl_xor(sj, m); dot += __shfl_xor(dot, m);
  }
  const float invi = 1.0f / sqrtf(si);
  const float invj = 1.0f / sqrtf(sj);
  union { u16 us[8]; uint4 v; } pk;
#pragma unroll
  for (int h = 0; h < 2; ++h) {
    pk.us[h*4+0] = f2bf(a[h].x * invi); pk.us[h*4+1] = f2bf(a[h].y * invi);
    pk.us[h*4+2] = f2bf(a[h].z * invi); pk.us[h*4+3] = f2bf(a[h].w * invi);
  }
  ((uint4*)(E + (size_t)k * DIM))[lane] = pk.v;
#pragma unroll
  for (int h = 0; h < 2; ++h) {
    pk.us[h*4+0] = f2bf(b[h].x * invj); pk.us[h*4+1] = f2bf(b[h].y * invj);
    pk.us[h*4+2] = f2bf(b[h].z * invj); pk.us[h*4+3] = f2bf(b[h].w * invj);
  }
  ((uint4*)(E + (size_t)(k + B_ROWS) * DIM))[lane] = pk.v;
  if (lane == 0) {
    pd[k] = dot * invi * invj;
    S[k] = 0.0f; S[k + B_ROWS] = 0.0f;
  }
}

// ---- symmetric Gram-GEMM, 3-buffer counted-vmcnt pipeline ----
__global__ __launch_bounds__(256) void ksimlse(const u16* __restrict__ E,
                                               float* __restrict__ S) {
  __shared__ u16 As[3][BM * BK];  // 3 x 8 KiB
  __shared__ u16 Bs[3][BN * BK];  // 3 x 8 KiB  (48 KiB total -> 3 blocks/CU)

  // triangular tile map: block t -> (I, J), J >= I, 64x64 tile grid
  const int t0 = blockIdx.x;
  int I = (int)(64.5f - sqrtf(4160.25f - 2.0f * (float)t0));
  if (I > 63) I = 63;
  int base = (129 * I - I * I) >> 1;
  if (base > t0) { --I; base = (129 * I - I * I) >> 1; }
  else {
    int nb = (129 * (I + 1) - (I + 1) * (I + 1)) >> 1;
    if (nb <= t0) { ++I; base = nb; }
  }
  const int J = I + (t0 - base);
  const int brow = I * BM, bcol = J * BN;
  const bool diag = (I == J);

  const int tid  = threadIdx.x;
  const int wid  = tid >> 6;
  const int lane = tid & 63;
  const int wr   = (wid >> 1) * 64;
  const int wc   = (wid & 1) * 64;
  const int g    = lane >> 4;
  const int lc   = lane & 15;

  const int    srow  = tid >> 2;
  const int    scol  = (tid & 3) * 8;
  const size_t aBase = (size_t)(brow + srow) * DIM + scol;
  const size_t bBase = (size_t)(bcol + srow) * DIM + scol;

  // stage K-step kk into buffer b: 4 global_load_lds (A it0, B it0, A it1, B it1)
  auto stage = [&](int b, int kk) {
#pragma unroll
    for (int it = 0; it < 2; ++it) {
      gload16(E + aBase + (size_t)it * 64 * DIM + kk,
              (char*)As + b * 8192 + it * 4096 + tid * 16);
      gload16(E + bBase + (size_t)it * 64 * DIM + kk,
              (char*)Bs + b * 8192 + it * 4096 + tid * 16);
    }
  };

  f32x4 acc[4][4] = {};

  // prologue: stage(0), stage(1); wait own stage(0) done (4 in flight ok)
  stage(0, 0);
  stage(1, BK);
  asm volatile("s_waitcnt vmcnt(4)\n\ts_barrier" ::: "memory");

#pragma unroll 1
  for (int t = 0; t < KSTEPS; ++t) {
    const int cur = t % 3;
    if (t + 2 < KSTEPS) stage((t + 2) % 3, (t + 2) * BK);  // issue-early

    bf16x8 af[4], bfr[4];
#pragma unroll
    for (int mi = 0; mi < 4; ++mi)
      af[mi] = *(const bf16x8*)&As[cur][(wr + mi * 16 + lc) * BK + g * 8];
#pragma unroll
    for (int ni = 0; ni < 4; ++ni)
      bfr[ni] = *(const bf16x8*)&Bs[cur][(wc + ni * 16 + lc) * BK + g * 8];
#pragma unroll
    for (int mi = 0; mi < 4; ++mi)
#pragma unroll
      for (int ni = 0; ni < 4; ++ni)
        acc[mi][ni] = __builtin_amdgcn_mfma_f32_16x16x32_bf16(
            af[mi], bfr[ni], acc[mi][ni], 0, 0, 0);

    // counted wait: stage(t+1) (issued last iter) must be done; stage(t+2)'s
    // 4 loads stay in flight. ds_reads above already drained by MFMA use.
    if (t < KSTEPS - 2) {
      asm volatile("s_waitcnt vmcnt(4)\n\ts_barrier" ::: "memory");
    } else if (t == KSTEPS - 2) {
      asm volatile("s_waitcnt vmcnt(0)\n\ts_barrier" ::: "memory");
    }  // t == KSTEPS-1: no barrier needed; epilogue uses no LDS
  }

  // epilogue: C/D layout col=lane&15, row=(lane>>4)*4+j  [m89/m91]
  float cs[4] = {0.f, 0.f, 0.f, 0.f};
#pragma unroll
  for (int mi = 0; mi < 4; ++mi) {
#pragma unroll
    for (int j = 0; j < 4; ++j) {
      const int Rg = brow + wr + mi * 16 + g * 4 + j;
      float rs = 0.0f;
#pragma unroll
      for (int ni = 0; ni < 4; ++ni) {
        const int Cg = bcol + wc + ni * 16 + lc;
        float e = __expf((acc[mi][ni][j] - 1.0f) * INV_TAU);
        if (diag && Rg == Cg) e = 0.0f;
        rs += e;
        cs[ni] += e;
      }
      rs += __shfl_xor(rs, 1);
      rs += __shfl_xor(rs, 2);
      rs += __shfl_xor(rs, 4);
      rs += __shfl_xor(rs, 8);
      if (lc == j) atomicAdd(&S[Rg], rs);
    }
  }
  if (!diag) {  // column sums -> S[c] (the mirrored half)
#pragma unroll
    for (int ni = 0; ni < 4; ++ni) {
      float c = cs[ni];
      c += __shfl_xor(c, 16);
      c += __shfl_xor(c, 32);
      if (g == 0) atomicAdd(&S[bcol + wc + ni * 16 + lc], c);
    }
  }
}

// ---- final: single block folds per-pair loss, no global atomics ----
__global__ __launch_bounds__(256) void kfinal256(const float* __restrict__ dist,
                                                 const float* __restrict__ pd,
                                                 const float* __restrict__ S,
                                                 float* __restrict__ out) {
  const int tid = threadIdx.x;
  float ls = 0.0f, nv = 0.0f;
  for (int it = 0; it < B_ROWS / 256; ++it) {
    const int k = it * 256 + tid;
    if (dist[k] < POS_THRESH) {
      ls += logf(S[k]) + logf(S[k + B_ROWS]) + 2.0f * INV_TAU
          - 2.0f * pd[k] * INV_TAU;
      nv += 2.0f;
    }
  }
#pragma unroll
  for (int m = 1; m < 64; m <<= 1) {
    ls += __shfl_xor(ls, m); nv += __shfl_xor(nv, m);
  }
  __shared__ float sl[4], sn[4];
  if ((tid & 63) == 0) { sl[tid >> 6] = ls; sn[tid >> 6] = nv; }
  __syncthreads();
  if (tid == 0) {
    const float L = sl[0] + sl[1] + sl[2] + sl[3];
    const float N = sn[0] + sn[1] + sn[2] + sn[3];
    out[0] = (N > 0.0f) ? (L / fmaxf(N, 1.0f)) : 0.0f;
  }
}

extern "C" void kernel_launch(void* const* d_in, const int* in_sizes, int n_in,
                              void* d_out, int out_size, void* d_ws, size_t ws_size,
                              hipStream_t stream) {
  const float* ei   = (const float*)d_in[0];
  const float* ej   = (const float*)d_in[1];
  const float* dist = (const float*)d_in[2];
  float* out = (float*)d_out;

  u16*   E  = (u16*)d_ws;
  float* S  = (float*)((char*)d_ws + (size_t)NROWS * DIM * sizeof(u16));
  float* pd = S + NROWS;

  knorm2<<<B_ROWS / 4, 256, 0, stream>>>(ei, ej, E, S, pd);
  ksimlse<<<NTILES, 256, 0, stream>>>(E, S);
  kfinal256<<<1, 256, 0, stream>>>(dist, pd, S, out);
}